// Round 3
// baseline (934.941 us; speedup 1.0000x reference)
//
#include <hip/hip_runtime.h>
#include <hip/hip_bf16.h>

// Problem constants
#define NB 8
#define NC 512
#define HW 4096
#define INNER 32

typedef unsigned short u16;
typedef unsigned int u32;

__device__ __forceinline__ float b2f(u16 u) {
    union { u32 a; float f; } z;
    z.a = ((u32)u) << 16;
    return z.f;
}

// Dtype-flexible input load. flag: 1 = fp32 tensors, 0 = bf16 tensors.
// Explicit if/else (NOT ?:) so the compiler cannot speculate the wrong-width
// load out of bounds.
__device__ __forceinline__ float ldin(const void* p, int idx, int isf32) {
    if (isf32) return ((const float*)p)[idx];
    return b2f(((const u16*)p)[idx]);
}

// ---------------------------------------------------------------------------
// Detect tensor dtype from bit patterns of `content`.
// bf16 N(0,1): u16 at even u16-index has exponent field in [100,150] w.p. ~1.
// fp32: that u16 is low mantissa bits -> exponent field uniform (P ~ 0.2).
// ---------------------------------------------------------------------------
__global__ __launch_bounds__(256) void k_detect(const u16* __restrict__ content,
                                                int* __restrict__ flag) {
    __shared__ int scnt;
    if (threadIdx.x == 0) scnt = 0;
    __syncthreads();
    u16 u = content[threadIdx.x * 2048];
    int e = (u >> 7) & 0xff;
    if (e >= 100 && e <= 150) atomicAdd(&scnt, 1);
    __syncthreads();
    if (threadIdx.x == 0) *flag = (scnt < 128) ? 1 : 0;   // 1 = fp32
}

// ---------------------------------------------------------------------------
// Transpose conv weights [O][J] -> [J][O] fp32
// ---------------------------------------------------------------------------
__global__ __launch_bounds__(256) void k_transpose(const void* __restrict__ src,
        float* __restrict__ dst, int O, int J, const int* __restrict__ flag) {
    int isf32 = *flag;
    int idx = blockIdx.x * 256 + threadIdx.x;
    if (idx >= O * J) return;
    int o = idx / J, j = idx - o * J;
    dst[j * O + o] = ldin(src, idx, isf32);
}

// ---------------------------------------------------------------------------
// Style stats: per (b,c) plane, 9 shifted window sums via inclusion-exclusion.
// mean(conv3x3_SAME(x))[o] = (1/HW)*sum_{c,k} w[o,c,k]*S[c,k] + bias[o]
// ---------------------------------------------------------------------------
__global__ __launch_bounds__(256) void k_style_stats(const void* __restrict__ style,
        float* __restrict__ S, const int* __restrict__ flag) {
    int isf32 = *flag;
    int bc = blockIdx.x;                        // b*512 + c
    int base = bc * HW;
    int tid = threadIdx.x;
    float t = 0.f, top = 0.f, bot = 0.f, lft = 0.f, rgt = 0.f;
    for (int e = tid; e < HW; e += 256) {
        float v = ldin(style, base + e, isf32);
        int h = e >> 6, w = e & 63;
        t += v;
        top += (h == 0)  ? v : 0.f;
        bot += (h == 63) ? v : 0.f;
        lft += (w == 0)  ? v : 0.f;
        rgt += (w == 63) ? v : 0.f;
    }
#pragma unroll
    for (int off = 32; off > 0; off >>= 1) {
        t   += __shfl_down(t, off);
        top += __shfl_down(top, off);
        bot += __shfl_down(bot, off);
        lft += __shfl_down(lft, off);
        rgt += __shfl_down(rgt, off);
    }
    __shared__ float red[4][5];
    int wave = tid >> 6;
    if ((tid & 63) == 0) {
        red[wave][0] = t; red[wave][1] = top; red[wave][2] = bot;
        red[wave][3] = lft; red[wave][4] = rgt;
    }
    __syncthreads();
    if (tid == 0) {
        t   = red[0][0] + red[1][0] + red[2][0] + red[3][0];
        top = red[0][1] + red[1][1] + red[2][1] + red[3][1];
        bot = red[0][2] + red[1][2] + red[2][2] + red[3][2];
        lft = red[0][3] + red[1][3] + red[2][3] + red[3][3];
        rgt = red[0][4] + red[1][4] + red[2][4] + red[3][4];
        float c00 = ldin(style, base + 0,    isf32);
        float c0W = ldin(style, base + 63,   isf32);
        float cH0 = ldin(style, base + 4032, isf32);
        float cHW = ldin(style, base + 4095, isf32);
        float* o = S + bc * 9;
        o[0] = t - bot - rgt + cHW;
        o[1] = t - bot;
        o[2] = t - bot - lft + cH0;
        o[3] = t - rgt;
        o[4] = t;
        o[5] = t - lft;
        o[6] = t - top - rgt + c0W;
        o[7] = t - top;
        o[8] = t - top - lft + c00;
    }
}

// ---------------------------------------------------------------------------
// pooled[set,b,o] = (1/4096)*sum_{c,k} cw[o,c,k]*S[b,c,k] + cb[o]
// ---------------------------------------------------------------------------
__global__ __launch_bounds__(64) void k_pooled(const float* __restrict__ S,
        const void* __restrict__ cw1, const void* __restrict__ cb1,
        const void* __restrict__ cw2, const void* __restrict__ cb2,
        float* __restrict__ pooled, const int* __restrict__ flag) {
    int isf32 = *flag;
    int set = blockIdx.y;
    int b = blockIdx.x >> 5;
    int o = blockIdx.x & 31;
    const void* cw = set ? cw2 : cw1;
    const void* cb = set ? cb2 : cb1;
    int lane = threadIdx.x;
    float acc = 0.f;
    const float* Sb = S + b * NC * 9;
    int wbase = o * NC * 9;
    for (int c = lane; c < NC; c += 64) {
#pragma unroll
        for (int k = 0; k < 9; k++)
            acc += Sb[c * 9 + k] * ldin(cw, wbase + c * 9 + k, isf32);
    }
#pragma unroll
    for (int off = 32; off > 0; off >>= 1) acc += __shfl_down(acc, off);
    if (lane == 0)
        pooled[(set * NB + b) * INNER + o] = acc * (1.0f / 4096.0f) + ldin(cb, o, isf32);
}

// ---------------------------------------------------------------------------
// FC: f[b,row] = pooled[b,:]·fw[row,:] + fb[row]; stored transposed:
// filtT[(set,b)][ (ic*9+k)*32 + oc ]   (row = oc*288 + ic*9 + k)
// ---------------------------------------------------------------------------
__global__ __launch_bounds__(256) void k_fc(const float* __restrict__ pooled,
        const void* __restrict__ fw1, const void* __restrict__ fb1,
        const void* __restrict__ fw2, const void* __restrict__ fb2,
        float* __restrict__ filtT, const int* __restrict__ flag) {
    int isf32 = *flag;
    int set = blockIdx.y;
    int b = blockIdx.x / 36;
    int chunk = blockIdx.x - b * 36;
    int row = chunk * 256 + threadIdx.x;       // 0..9215
    const void* fw = set ? fw2 : fw1;
    const void* fb = set ? fb2 : fb1;
    __shared__ float p[32];
    if (threadIdx.x < 32) p[threadIdx.x] = pooled[(set * NB + b) * 32 + threadIdx.x];
    __syncthreads();
    float acc = ldin(fb, row, isf32);
    if (isf32) {
        const float* fwf = (const float*)fw + row * 32;
#pragma unroll
        for (int j = 0; j < 32; j++) acc += fwf[j] * p[j];
    } else {
        const u32* w32 = (const u32*)((const u16*)fw + row * 32);
#pragma unroll
        for (int j = 0; j < 16; j++) {
            u32 u = w32[j];
            acc += b2f((u16)(u & 0xffffu)) * p[2 * j];
            acc += b2f((u16)(u >> 16)) * p[2 * j + 1];
        }
    }
    int o = row / 288;
    int rem = row - o * 288;
    filtT[(set * NB + b) * 9216 + rem * 32 + o] = acc;
}

// ---------------------------------------------------------------------------
// Conv 512->32 on content -> c0 (fp32). One block per (b,row).
// 256 threads = 64 cols x 4 output-groups of 8. wT[(c*9+k)*32+o] fp32.
// ---------------------------------------------------------------------------
__global__ __launch_bounds__(256) void k_conv_down(const void* __restrict__ content,
        const float* __restrict__ wT, const void* __restrict__ dsb,
        float* __restrict__ c0, const int* __restrict__ flag) {
    int isf32 = *flag;
    int b = blockIdx.x >> 6, row = blockIdx.x & 63;
    int tid = threadIdx.x, col = tid & 63;
    int g = __builtin_amdgcn_readfirstlane(tid >> 6);   // 0..3, wave-uniform
    __shared__ float lds[32 * 198];                     // 32 ch x 3 rows x 66 cols
    float acc[8];
#pragma unroll
    for (int o = 0; o < 8; o++) acc[o] = 0.f;
    int cbase = b * NC * HW;

    for (int cc = 0; cc < NC; cc += 32) {
        if (cc) __syncthreads();
        for (int idx = tid; idx < 32 * 198; idx += 256) {
            int c = idx / 198;
            int rem = idx - c * 198;
            int r = rem / 66;
            int w = rem - r * 66 - 1;                   // -1..64
            int gh = row + r - 1;
            float v = 0.f;
            if (gh >= 0 && gh < 64 && (unsigned)w < 64u)
                v = ldin(content, cbase + (cc + c) * HW + gh * 64 + w, isf32);
            lds[idx] = v;
        }
        __syncthreads();
        for (int c = 0; c < 32; c++) {
            float x[9];
#pragma unroll
            for (int r = 0; r < 3; r++)
#pragma unroll
                for (int dw = 0; dw < 3; dw++)
                    x[r * 3 + dw] = lds[c * 198 + r * 66 + col + dw];
            const float* wp = wT + (cc + c) * 9 * 32 + g * 8;
#pragma unroll
            for (int k = 0; k < 9; k++) {
                float xv = x[k];
#pragma unroll
                for (int o = 0; o < 8; o++) acc[o] += xv * wp[k * 32 + o];
            }
        }
    }
#pragma unroll
    for (int o = 0; o < 8; o++) {
        int oc = g * 8 + o;
        c0[(b * INNER + oc) * HW + row * 64 + col] = acc[o] + ldin(dsb, oc, isf32);
    }
}

// ---------------------------------------------------------------------------
// Per-sample dynamic 32->32 conv (+ optional LeakyReLU). fp32 src.
// dstBf16: 0 -> fp32 dst, 1 -> bf16 dst.
// ---------------------------------------------------------------------------
__global__ __launch_bounds__(256) void k_apply(const float* __restrict__ src,
        const float* __restrict__ filtT, void* __restrict__ dst,
        int lrelu, int dstBf16) {
    int b = blockIdx.x >> 6, row = blockIdx.x & 63;
    int tid = threadIdx.x, col = tid & 63;
    int g = __builtin_amdgcn_readfirstlane(tid >> 6);
    __shared__ float lds[32 * 198];
    const float* sp = src + b * INNER * HW;
    for (int idx = tid; idx < 32 * 198; idx += 256) {
        int c = idx / 198;
        int rem = idx - c * 198;
        int r = rem / 66;
        int w = rem - r * 66 - 1;
        int gh = row + r - 1;
        float v = 0.f;
        if (gh >= 0 && gh < 64 && (unsigned)w < 64u)
            v = sp[c * HW + gh * 64 + w];
        lds[idx] = v;
    }
    __syncthreads();
    float acc[8];
#pragma unroll
    for (int o = 0; o < 8; o++) acc[o] = 0.f;
    const float* fbp = filtT + b * 9216 + g * 8;
    for (int c = 0; c < 32; c++) {
        float x[9];
#pragma unroll
        for (int r = 0; r < 3; r++)
#pragma unroll
            for (int dw = 0; dw < 3; dw++)
                x[r * 3 + dw] = lds[c * 198 + r * 66 + col + dw];
        const float* wp = fbp + c * 288;
#pragma unroll
        for (int k = 0; k < 9; k++) {
            float xv = x[k];
#pragma unroll
            for (int o = 0; o < 8; o++) acc[o] += xv * wp[k * 32 + o];
        }
    }
#pragma unroll
    for (int o = 0; o < 8; o++) {
        float v = acc[o];
        if (lrelu) v = (v >= 0.f) ? v : 0.2f * v;
        int di = (b * INNER + g * 8 + o) * HW + row * 64 + col;
        if (dstBf16) ((__hip_bfloat16*)dst)[di] = __float2bfloat16(v);
        else         ((float*)dst)[di] = v;
    }
}

// ---------------------------------------------------------------------------
// Conv 32->512 (+bias) + residual content -> out (dtype per flag).
// c2 is bf16. One block per (b,row); 8 passes over output channels.
// ---------------------------------------------------------------------------
__global__ __launch_bounds__(256) void k_conv_up(const u16* __restrict__ c2,
        const float* __restrict__ wT, const void* __restrict__ upb,
        const void* __restrict__ content, void* __restrict__ outv,
        const int* __restrict__ flag) {
    int isf32 = *flag;
    int b = blockIdx.x >> 6, row = blockIdx.x & 63;
    int tid = threadIdx.x, col = tid & 63;
    int g = __builtin_amdgcn_readfirstlane(tid >> 6);   // 0..3
    __shared__ float lds[32 * 198];
    const u16* sp = c2 + b * INNER * HW;
    for (int idx = tid; idx < 32 * 198; idx += 256) {
        int c = idx / 198;
        int rem = idx - c * 198;
        int r = rem / 66;
        int w = rem - r * 66 - 1;
        int gh = row + r - 1;
        float v = 0.f;
        if (gh >= 0 && gh < 64 && (unsigned)w < 64u)
            v = b2f(sp[c * HW + gh * 64 + w]);
        lds[idx] = v;
    }
    __syncthreads();

    for (int pass = 0; pass < 8; pass++) {
        float acc[16];
#pragma unroll
        for (int o = 0; o < 16; o++) acc[o] = 0.f;
        for (int c = 0; c < 32; c++) {
            float x[9];
#pragma unroll
            for (int r = 0; r < 3; r++)
#pragma unroll
                for (int dw = 0; dw < 3; dw++)
                    x[r * 3 + dw] = lds[c * 198 + r * 66 + col + dw];
            const float* wp = wT + c * 9 * 512 + pass * 64 + g * 16;
#pragma unroll
            for (int k = 0; k < 9; k++) {
                float xv = x[k];
#pragma unroll
                for (int o = 0; o < 16; o++) acc[o] += xv * wp[k * 512 + o];
            }
        }
#pragma unroll
        for (int o = 0; o < 16; o++) {
            int oc = pass * 64 + g * 16 + o;
            int idx = (b * NC + oc) * HW + row * 64 + col;
            float v = acc[o] + ldin(upb, oc, isf32) + ldin(content, idx, isf32);
            if (isf32) ((float*)outv)[idx] = v;
            else       ((__hip_bfloat16*)outv)[idx] = __float2bfloat16(v);
        }
    }
}

// ---------------------------------------------------------------------------
extern "C" void kernel_launch(void* const* d_in, const int* in_sizes, int n_in,
                              void* d_out, int out_size, void* d_ws, size_t ws_size,
                              hipStream_t stream) {
    const void* content = d_in[0];
    const void* style   = d_in[1];
    const void* ds_w    = d_in[2];
    const void* ds_b    = d_in[3];
    const void* up_w    = d_in[4];
    const void* up_b    = d_in[5];
    const void* f1_cw   = d_in[6];
    const void* f1_cb   = d_in[7];
    const void* f1_fw   = d_in[8];
    const void* f1_fb   = d_in[9];
    const void* f2_cw   = d_in[10];
    const void* f2_cb   = d_in[11];
    const void* f2_fw   = d_in[12];
    const void* f2_fb   = d_in[13];

    // d_out doubles as scratch for everything DEAD before the final kernel.
    // Worst-case capacity (bf16 out): 16,777,216*2 B = 8,388,608 floats.
    // Used: 2,429,440 floats. The final kernel reads NOTHING from d_out.
    float* dscr   = (float*)d_out;
    float* c0     = dscr;                  // 1,048,576
    float* c1     = c0 + 1048576;          // 1,048,576
    float* wTds   = c1 + 1048576;          //   147,456
    float* S      = wTds + 147456;         //    36,864
    float* pooled = S + 36864;             //       512
    float* filtT  = pooled + 512;          //   147,456 (both sets)

    // d_ws holds ONLY what the final kernel reads: 2,687,008 bytes total.
    int*   flag = (int*)d_ws;
    float* wTup = (float*)((char*)d_ws + 16);        // 147,456 fp32
    u16*   c2   = (u16*)(wTup + 147456);             // 1,048,576 bf16

    k_detect<<<1, 256, 0, stream>>>((const u16*)content, flag);
    k_transpose<<<576, 256, 0, stream>>>(ds_w, wTds, 32, 4608, flag);
    k_transpose<<<576, 256, 0, stream>>>(up_w, wTup, 512, 288, flag);
    k_style_stats<<<NB * NC, 256, 0, stream>>>(style, S, flag);
    k_pooled<<<dim3(NB * 32, 2), 64, 0, stream>>>(S, f1_cw, f1_cb, f2_cw, f2_cb, pooled, flag);
    k_fc<<<dim3(NB * 36, 2), 256, 0, stream>>>(pooled, f1_fw, f1_fb, f2_fw, f2_fb, filtT, flag);
    k_conv_down<<<NB * 64, 256, 0, stream>>>(content, wTds, ds_b, c0, flag);
    k_apply<<<NB * 64, 256, 0, stream>>>(c0, filtT, c1, 1, 0);
    k_apply<<<NB * 64, 256, 0, stream>>>(c1, filtT + NB * 9216, c2, 0, 1);
    k_conv_up<<<NB * 64, 256, 0, stream>>>(c2, wTup, up_b, content, d_out, flag);
}